// Round 2
// baseline (345.172 us; speedup 1.0000x reference)
//
#include <hip/hip_runtime.h>

#define NB 32
#define NF 1024
#define ND 64
#define NH 4

typedef __attribute__((ext_vector_type(8))) short bf16x8;
typedef __attribute__((ext_vector_type(4))) float f32x4;

#define MFMA __builtin_amdgcn_mfma_f32_16x16x32_bf16

__device__ __forceinline__ unsigned short f2bf(float f){
  unsigned u = __float_as_uint(f);
  u += 0x7fffu + ((u >> 16) & 1u);
  return (unsigned short)(u >> 16);
}
__device__ __forceinline__ float bf2f(unsigned short h){
  return __uint_as_float(((unsigned)h) << 16);
}
// pack fp32 as (hi bf16) | (lo bf16 << 16), hi = RNE(v), lo = RNE(v - hi)
__device__ __forceinline__ unsigned packsplit(float v){
  unsigned short h = f2bf(v);
  unsigned short l = f2bf(v - bf2f(h));
  return (unsigned)h | ((unsigned)l << 16);
}

// Swizzled bf16 LDS tile addressing. rsc = row stride in 16B chunks
// (8 for 64-wide tiles, 32 for 256-wide). Chunk index XOR (row&7)
// spreads the 128B-stride column accesses across banks (<=2-way per m136).
__device__ __forceinline__ int toff(int row, int col, int rsc){
  int ch = (col >> 3) ^ (row & 7);
  return (row * rsc + ch) * 16 + (col & 7) * 2;
}
__device__ __forceinline__ bf16x8 frag_ld(const char* t, int row, int col0, int rsc){
  return *(const bf16x8*)(t + (row * rsc + (((col0) >> 3) ^ (row & 7))) * 16);
}
__device__ __forceinline__ void st16(char* t, int row, int col, int rsc, unsigned short v){
  *(unsigned short*)(t + toff(row, col, rsc)) = v;
}

// ---------------- Kernel 1: QKV projection ----------------
// grid: NB*16*NH blocks, 64 threads (1 wave). block -> (b, ftile, h).
// Q,K stored [b][h][f][d] as packed pair-dwords; V stored transposed [b][h][d][g].
__global__ __launch_bounds__(64, 1) void k_qkv(const float* __restrict__ x,
        const float* __restrict__ Wq,
        unsigned* __restrict__ Qp, unsigned* __restrict__ Kp, unsigned* __restrict__ Vtp){
  int blk = blockIdx.x;
  int h = blk & 3, ft = (blk >> 2) & 15, b = blk >> 6;
  int f0 = ft << 6;
  int l = threadIdx.x;
  int l15 = l & 15, lg = l >> 4;
  __shared__ char xh[8192], xl[8192], wth[8192], wtl[8192];

  { // stage x row l as hi/lo bf16 (swizzled chunks)
    const float* xs = x + ((size_t)(b * NF) + f0 + l) * ND;
    #pragma unroll
    for(int c = 0; c < 8; c++){
      float4 v4a = *(const float4*)(xs + c * 8);
      float4 v4b = *(const float4*)(xs + c * 8 + 4);
      float vv[8] = {v4a.x, v4a.y, v4a.z, v4a.w, v4b.x, v4b.y, v4b.z, v4b.w};
      bf16x8 vh, vl;
      #pragma unroll
      for(int j = 0; j < 8; j++){
        unsigned short hh = f2bf(vv[j]);
        vh[j] = (short)hh;
        vl[j] = (short)f2bf(vv[j] - bf2f(hh));
      }
      int off = (l * 8 + (c ^ (l & 7))) * 16;
      *(bf16x8*)(xh + off) = vh;
      *(bf16x8*)(xl + off) = vl;
    }
  }

  for(int slot = 0; slot < 3; slot++){
    { // stage W^T for (h, slot), coalesced: iter i reads W[i][l], writes wt[l][i]
      const float* wsl = Wq + ((size_t)h * 3 + slot) * ND * ND;
      #pragma unroll 8
      for(int i = 0; i < 64; i++){
        float v = wsl[i * 64 + l];
        unsigned short hh = f2bf(v);
        st16(wth, l, i, 8, hh);
        st16(wtl, l, i, 8, f2bf(v - bf2f(hh)));
      }
    }
    __syncthreads();
    f32x4 acc[4][4];
    #pragma unroll
    for(int i = 0; i < 4; i++)
      #pragma unroll
      for(int j = 0; j < 4; j++)
        acc[i][j] = (f32x4){0.f, 0.f, 0.f, 0.f};
    #pragma unroll
    for(int ks = 0; ks < 2; ks++){
      int kc = ks * 32 + lg * 8;
      bf16x8 ah[4], al[4], bh[4], bl[4];
      #pragma unroll
      for(int mt = 0; mt < 4; mt++){
        ah[mt] = frag_ld(xh, mt * 16 + l15, kc, 8);
        al[mt] = frag_ld(xl, mt * 16 + l15, kc, 8);
      }
      #pragma unroll
      for(int nt = 0; nt < 4; nt++){
        bh[nt] = frag_ld(wth, nt * 16 + l15, kc, 8);
        bl[nt] = frag_ld(wtl, nt * 16 + l15, kc, 8);
      }
      __builtin_amdgcn_s_setprio(1);
      #pragma unroll
      for(int mt = 0; mt < 4; mt++)
        #pragma unroll
        for(int nt = 0; nt < 4; nt++){
          acc[mt][nt] = MFMA(ah[mt], bh[nt], acc[mt][nt], 0, 0, 0);
          acc[mt][nt] = MFMA(ah[mt], bl[nt], acc[mt][nt], 0, 0, 0);
          acc[mt][nt] = MFMA(al[mt], bh[nt], acc[mt][nt], 0, 0, 0);
        }
      __builtin_amdgcn_s_setprio(0);
    }
    __syncthreads();
    if(slot < 2){
      unsigned* dst = (slot == 0 ? Qp : Kp) + ((size_t)(b * NH + h) * NF + f0) * ND;
      #pragma unroll
      for(int mt = 0; mt < 4; mt++)
        #pragma unroll
        for(int nt = 0; nt < 4; nt++)
          #pragma unroll
          for(int jj = 0; jj < 4; jj++){
            int row = mt * 16 + lg * 4 + jj, col = nt * 16 + l15;
            dst[row * ND + col] = packsplit(acc[mt][nt][jj]);
          }
    } else {
      unsigned* dst = Vtp + (size_t)(b * NH + h) * ND * NF;
      #pragma unroll
      for(int mt = 0; mt < 4; mt++)
        #pragma unroll
        for(int nt = 0; nt < 4; nt++){
          int col = nt * 16 + l15;
          int g = f0 + mt * 16 + lg * 4;
          uint4 pv;
          pv.x = packsplit(acc[mt][nt][0]);
          pv.y = packsplit(acc[mt][nt][1]);
          pv.z = packsplit(acc[mt][nt][2]);
          pv.w = packsplit(acc[mt][nt][3]);
          *(uint4*)(dst + (size_t)col * NF + g) = pv;
        }
    }
  }
}

// ---------------- Kernel 2: fused attention + proj + LN ----------------
// grid: NB*16 blocks, 256 threads (4 waves; wave w = head w). LDS 147712 B.
// blockIdx remapped so all 16 f-tiles of one b land on one XCD (K/V L2 reuse).
__global__ __launch_bounds__(256, 1) void k_attn(const float* __restrict__ x,
    const unsigned* __restrict__ Qp, const unsigned* __restrict__ Kp,
    const unsigned* __restrict__ Vtp,
    const float* __restrict__ Wo, const float* __restrict__ bo,
    const float* __restrict__ gam, const float* __restrict__ bet,
    float* __restrict__ out){
  // 512 blocks = 8 XCDs * 64. Dispatch is round-robin (blk % 8 = XCD).
  // XCD x gets b in {x, x+8, x+16, x+24}, consecutive j = same b (temporal locality).
  int blk0 = blockIdx.x;
  int xcd = blk0 & 7, j = blk0 >> 3;
  int b = xcd + ((j >> 4) << 3);
  int f0 = (j & 15) << 6;
  int t = threadIdx.x;
  int w = t >> 6, l = t & 63;
  int l15 = l & 15, lg = l >> 4;
  extern __shared__ char sm[];
  // phase 1: per-wave buffers, 32KB each
  char* kvh = sm + w * 32768;
  char* kvl = kvh + 8192;
  char* sh  = kvh + 16384;
  char* sl  = kvh + 24576;

  // Q fragments (hi/lo) for the whole kernel, straight from global
  bf16x8 qh[4][2], ql[4][2];
  {
    const unsigned* qb = Qp + ((size_t)(b * NH + w) * NF + f0) * ND;
    #pragma unroll
    for(int mt = 0; mt < 4; mt++)
      #pragma unroll
      for(int ks = 0; ks < 2; ks++){
        const uint4* p = (const uint4*)(qb + (mt * 16 + l15) * ND + ks * 32 + lg * 8);
        uint4 a = p[0], c = p[1];
        unsigned pr[8] = {a.x, a.y, a.z, a.w, c.x, c.y, c.z, c.w};
        bf16x8 vh, vl;
        #pragma unroll
        for(int j2 = 0; j2 < 8; j2++){
          vh[j2] = (short)(pr[j2] & 0xffffu);
          vl[j2] = (short)(pr[j2] >> 16);
        }
        qh[mt][ks] = vh; ql[mt][ks] = vl;
      }
  }

  f32x4 oa[4][4];
  #pragma unroll
  for(int i = 0; i < 4; i++)
    #pragma unroll
    for(int j2 = 0; j2 < 4; j2++)
      oa[i][j2] = (f32x4){0.f, 0.f, 0.f, 0.f};

  const uint4* Kb = (const uint4*)(Kp + (size_t)(b * NH + w) * NF * ND);
  const uint4* Vb = (const uint4*)(Vtp + (size_t)(b * NH + w) * ND * NF);

  // T14 pipeline: one 16-uint4 register buffer, consume-then-reissue.
  uint4 pre[16];
  auto issueK = [&](int g0){
    const uint4* s_ = Kb + (size_t)(g0 + l) * 16;      // row g0+l, 64 dwords
    #pragma unroll
    for(int c = 0; c < 16; c++) pre[c] = s_[c];
  };
  auto issueV = [&](int g0){
    const uint4* s_ = Vb + (size_t)l * 256 + (g0 >> 2); // row d=l, cols g0..g0+63
    #pragma unroll
    for(int c = 0; c < 16; c++) pre[c] = s_[c];
  };
  auto wrlds = [&](){   // de-interleave 64 pair-dwords into kvh/kvl (waits the vmem)
    #pragma unroll
    for(int c = 0; c < 8; c++){
      uint4 a = pre[2 * c], d = pre[2 * c + 1];
      unsigned pr[8] = {a.x, a.y, a.z, a.w, d.x, d.y, d.z, d.w};
      bf16x8 vh, vl;
      #pragma unroll
      for(int j2 = 0; j2 < 8; j2++){
        vh[j2] = (short)(pr[j2] & 0xffffu);
        vl[j2] = (short)(pr[j2] >> 16);
      }
      int off = (l * 8 + (c ^ (l & 7))) * 16;
      *(bf16x8*)(kvh + off) = vh;
      *(bf16x8*)(kvl + off) = vl;
    }
  };

  issueK(0);
  for(int kt = 0; kt < 16; kt++){
    wrlds();                                  // K tile -> LDS
    issueV(kt << 6);                          // V loads fly under QK^T
    asm volatile("s_waitcnt lgkmcnt(0)" ::: "memory");

    // S = Q K^T
    f32x4 s[4][4];
    #pragma unroll
    for(int i = 0; i < 4; i++)
      #pragma unroll
      for(int j2 = 0; j2 < 4; j2++)
        s[i][j2] = (f32x4){0.f, 0.f, 0.f, 0.f};
    #pragma unroll
    for(int ks = 0; ks < 2; ks++){
      int kc = ks * 32 + lg * 8;
      bf16x8 bh[4], bl2[4];
      #pragma unroll
      for(int nt = 0; nt < 4; nt++){
        bh[nt]  = frag_ld(kvh, nt * 16 + l15, kc, 8);
        bl2[nt] = frag_ld(kvl, nt * 16 + l15, kc, 8);
      }
      __builtin_amdgcn_s_setprio(1);
      #pragma unroll
      for(int mt = 0; mt < 4; mt++)
        #pragma unroll
        for(int nt = 0; nt < 4; nt++){
          s[mt][nt] = MFMA(qh[mt][ks], bh[nt],  s[mt][nt], 0, 0, 0);
          s[mt][nt] = MFMA(qh[mt][ks], bl2[nt], s[mt][nt], 0, 0, 0);
          s[mt][nt] = MFMA(ql[mt][ks], bh[nt],  s[mt][nt], 0, 0, 0);
        }
      __builtin_amdgcn_s_setprio(0);
    }
    // relu(s/8), split to bf16 pair tiles
    #pragma unroll
    for(int mt = 0; mt < 4; mt++)
      #pragma unroll
      for(int nt = 0; nt < 4; nt++)
        #pragma unroll
        for(int jj = 0; jj < 4; jj++){
          float v = fmaxf(s[mt][nt][jj] * 0.125f, 0.f);
          unsigned short hh = f2bf(v);
          int row = mt * 16 + lg * 4 + jj, col = nt * 16 + l15;
          st16(sh, row, col, 8, hh);
          st16(sl, row, col, 8, f2bf(v - bf2f(hh)));
        }
    wrlds();                                  // V tile -> LDS (overwrites K buf)
    issueK(((kt + 1) & 15) << 6);             // next K flies under PV
    asm volatile("s_waitcnt lgkmcnt(0)" ::: "memory");

    // O += S V
    #pragma unroll
    for(int ks = 0; ks < 2; ks++){
      int kc = ks * 32 + lg * 8;
      bf16x8 sah[4], sal[4];
      #pragma unroll
      for(int mt = 0; mt < 4; mt++){
        sah[mt] = frag_ld(sh, mt * 16 + l15, kc, 8);
        sal[mt] = frag_ld(sl, mt * 16 + l15, kc, 8);
      }
      #pragma unroll
      for(int nt = 0; nt < 4; nt++){
        bf16x8 vbh = frag_ld(kvh, nt * 16 + l15, kc, 8);
        bf16x8 vbl = frag_ld(kvl, nt * 16 + l15, kc, 8);
        __builtin_amdgcn_s_setprio(1);
        #pragma unroll
        for(int mt = 0; mt < 4; mt++){
          oa[mt][nt] = MFMA(sah[mt], vbh, oa[mt][nt], 0, 0, 0);
          oa[mt][nt] = MFMA(sah[mt], vbl, oa[mt][nt], 0, 0, 0);
          oa[mt][nt] = MFMA(sal[mt], vbh, oa[mt][nt], 0, 0, 0);
        }
        __builtin_amdgcn_s_setprio(0);
      }
    }
  }

  __syncthreads();   // phase boundary: repurpose all LDS

  // phase 2 layout
  char* ch = sm;                     // concat hi  [64][256]
  char* cl = sm + 32768;             // concat lo
  char* wh = sm + 65536;             // Wo^T hi    [64][256] (row=o, col=k)
  char* wl = sm + 98304;             // Wo^T lo
  float* xr = (float*)(sm + 131072); // residual   [64][65]

  // write O fragments into concat stripe for this head
  #pragma unroll
  for(int mt = 0; mt < 4; mt++)
    #pragma unroll
    for(int nt = 0; nt < 4; nt++)
      #pragma unroll
      for(int jj = 0; jj < 4; jj++){
        float v = oa[mt][nt][jj];
        unsigned short hh = f2bf(v);
        int row = mt * 16 + lg * 4 + jj, col = (w << 6) + nt * 16 + l15;
        st16(ch, row, col, 32, hh);
        st16(cl, row, col, 32, f2bf(v - bf2f(hh)));
      }
  { // build Wo^T coalesced: iter i, elem e=i*256+t of Wo[256][64]; write col k=e>>6
    #pragma unroll 8
    for(int i = 0; i < 64; i++){
      int e = i * 256 + t;
      int k = e >> 6, o = e & 63;
      float v = Wo[e];
      unsigned short hh = f2bf(v);
      st16(wh, o, k, 32, hh);
      st16(wl, o, k, 32, f2bf(v - bf2f(hh)));
    }
  }
  { // stage residual x tile fp32
    int r = t >> 2, c0 = (t & 3) << 4;
    const float* xs = x + ((size_t)(b * NF) + f0 + r) * ND + c0;
    #pragma unroll
    for(int i = 0; i < 4; i++)
      *(float4*)(xr + r * 65 + c0 + i * 4) = *(const float4*)(xs + i * 4);
  }
  __syncthreads();

  // proj: wave w computes output rows w*16 .. w*16+15 over K=256
  f32x4 p[4];
  #pragma unroll
  for(int i = 0; i < 4; i++) p[i] = (f32x4){0.f, 0.f, 0.f, 0.f};
  #pragma unroll
  for(int ks = 0; ks < 8; ks++){
    int kc = ks * 32 + lg * 8;
    bf16x8 ah  = frag_ld(ch, (w << 4) + l15, kc, 32);
    bf16x8 al2 = frag_ld(cl, (w << 4) + l15, kc, 32);
    #pragma unroll
    for(int nt = 0; nt < 4; nt++){
      bf16x8 bh2 = frag_ld(wh, nt * 16 + l15, kc, 32);
      bf16x8 bl3 = frag_ld(wl, nt * 16 + l15, kc, 32);
      __builtin_amdgcn_s_setprio(1);
      p[nt] = MFMA(ah,  bh2, p[nt], 0, 0, 0);
      p[nt] = MFMA(ah,  bl3, p[nt], 0, 0, 0);
      p[nt] = MFMA(al2, bh2, p[nt], 0, 0, 0);
      __builtin_amdgcn_s_setprio(0);
    }
  }

  float bov[4], gv[4], bv[4];
  #pragma unroll
  for(int nt = 0; nt < 4; nt++){
    int col = nt * 16 + l15;
    bov[nt] = bo[col]; gv[nt] = gam[col]; bv[nt] = bet[col];
  }
  #pragma unroll
  for(int jj = 0; jj < 4; jj++){
    int row = (w << 4) + lg * 4 + jj;
    float vals[4], s1 = 0.f, s2 = 0.f;
    #pragma unroll
    for(int nt = 0; nt < 4; nt++){
      int col = nt * 16 + l15;
      float v = p[nt][jj] + bov[nt] + xr[row * 65 + col];
      vals[nt] = v; s1 += v; s2 += v * v;
    }
    #pragma unroll
    for(int m = 1; m < 16; m <<= 1){
      s1 += __shfl_xor(s1, m, 64);
      s2 += __shfl_xor(s2, m, 64);
    }
    float mean = s1 * (1.f / 64.f);
    float var  = s2 * (1.f / 64.f) - mean * mean;
    float rs = rsqrtf(var + 1e-5f);
    #pragma unroll
    for(int nt = 0; nt < 4; nt++){
      int col = nt * 16 + l15;
      out[((size_t)(b * NF) + f0 + row) * ND + col] = (vals[nt] - mean) * rs * gv[nt] + bv[nt];
    }
  }
}

extern "C" void kernel_launch(void* const* d_in, const int* in_sizes, int n_in,
                              void* d_out, int out_size, void* d_ws, size_t ws_size,
                              hipStream_t stream){
  const float* x   = (const float*)d_in[0];
  const float* Wq  = (const float*)d_in[1];
  const float* Wo  = (const float*)d_in[2];
  const float* bo  = (const float*)d_in[3];
  const float* gam = (const float*)d_in[4];
  const float* bet = (const float*)d_in[5];
  float* out = (float*)d_out;

  // workspace: Q, K as [B][H][F][D] pair-dwords; V^T as [B][H][D][F]. 100.7 MB total.
  unsigned* Qp = (unsigned*)d_ws;
  size_t n1 = (size_t)NB * NH * NF * ND;
  unsigned* Kp  = Qp + n1;
  unsigned* Vtp = Kp + n1;

  (void)in_sizes; (void)n_in; (void)out_size; (void)ws_size;

  hipFuncSetAttribute((const void*)k_attn,
                      hipFuncAttributeMaxDynamicSharedMemorySize, 147712);

  k_qkv<<<dim3(NB * 16 * NH), dim3(64), 0, stream>>>(x, Wq, Qp, Kp, Vtp);
  k_attn<<<dim3(NB * 16), dim3(256), 147712, stream>>>(x, Qp, Kp, Vtp, Wo, bo, gam, bet, out);
}

// Round 8
// 268.147 us; speedup vs baseline: 1.2872x; 1.2872x over previous
//
#include <hip/hip_runtime.h>

#define NB 32
#define NF 1024
#define ND 64
#define NH 4

typedef __attribute__((ext_vector_type(8))) short bf16x8;
typedef __attribute__((ext_vector_type(4))) float f32x4;

#define MFMA16 __builtin_amdgcn_mfma_f32_16x16x32_bf16

__device__ __forceinline__ unsigned short f2bf(float f){
  unsigned u = __float_as_uint(f);
  u += 0x7fffu + ((u >> 16) & 1u);
  return (unsigned short)(u >> 16);
}
__device__ __forceinline__ float bf2f(unsigned short h){
  return __uint_as_float(((unsigned)h) << 16);
}
// pack fp32 as (hi bf16) | (lo bf16 << 16)
__device__ __forceinline__ unsigned packsplit(float v){
  unsigned short h = f2bf(v);
  unsigned short l = f2bf(v - bf2f(h));
  return (unsigned)h | ((unsigned)l << 16);
}
// R2-verbatim swizzled LDS helpers (rsc = row stride in 16B chunks)
__device__ __forceinline__ int toff(int row, int col, int rsc){
  int ch = (col >> 3) ^ (row & 7);
  return (row * rsc + ch) * 16 + (col & 7) * 2;
}
__device__ __forceinline__ bf16x8 frag_ld(const char* t, int row, int col0, int rsc){
  return *(const bf16x8*)(t + (row * rsc + (((col0) >> 3) ^ (row & 7))) * 16);
}
__device__ __forceinline__ void st16(char* t, int row, int col, int rsc, unsigned short v){
  *(unsigned short*)(t + toff(row, col, rsc)) = v;
}
// de-interleave 8 packed pair-dwords -> hi/lo bf16x8 (R2-verbatim bit ops)
__device__ __forceinline__ void deint(uint4 a, uint4 d, bf16x8& hi, bf16x8& lo){
  unsigned pr[8] = {a.x, a.y, a.z, a.w, d.x, d.y, d.z, d.w};
  bf16x8 vh, vl;
  #pragma unroll
  for(int j2 = 0; j2 < 8; j2++){
    vh[j2] = (short)(pr[j2] & 0xffffu);
    vl[j2] = (short)(pr[j2] >> 16);
  }
  hi = vh; lo = vl;
}

// ---------------- Kernel 1: QKV projection (R2-verbatim, PASSED) ----------------
// grid: NB*16*NH blocks, 64 threads (1 wave). block -> (b, ftile, h).
// Q,K stored [b][h][f][d] as packed pair-dwords; V stored transposed [b][h][d][g].
__global__ __launch_bounds__(64, 1) void k_qkv(const float* __restrict__ x,
        const float* __restrict__ Wq,
        unsigned* __restrict__ Qp, unsigned* __restrict__ Kp, unsigned* __restrict__ Vtp){
  int blk = blockIdx.x;
  int h = blk & 3, ft = (blk >> 2) & 15, b = blk >> 6;
  int f0 = ft << 6;
  int l = threadIdx.x;
  int l15 = l & 15, lg = l >> 4;
  __shared__ char xh[8192], xl[8192], wth[8192], wtl[8192];

  { // stage x row l as hi/lo bf16 (swizzled chunks)
    const float* xs = x + ((size_t)(b * NF) + f0 + l) * ND;
    #pragma unroll
    for(int c = 0; c < 8; c++){
      float4 v4a = *(const float4*)(xs + c * 8);
      float4 v4b = *(const float4*)(xs + c * 8 + 4);
      float vv[8] = {v4a.x, v4a.y, v4a.z, v4a.w, v4b.x, v4b.y, v4b.z, v4b.w};
      bf16x8 vh, vl;
      #pragma unroll
      for(int j = 0; j < 8; j++){
        unsigned short hh = f2bf(vv[j]);
        vh[j] = (short)hh;
        vl[j] = (short)f2bf(vv[j] - bf2f(hh));
      }
      int off = (l * 8 + (c ^ (l & 7))) * 16;
      *(bf16x8*)(xh + off) = vh;
      *(bf16x8*)(xl + off) = vl;
    }
  }

  for(int slot = 0; slot < 3; slot++){
    { // stage W^T for (h, slot), coalesced: iter i reads W[i][l], writes wt[l][i]
      const float* wsl = Wq + ((size_t)h * 3 + slot) * ND * ND;
      #pragma unroll 8
      for(int i = 0; i < 64; i++){
        float v = wsl[i * 64 + l];
        unsigned short hh = f2bf(v);
        st16(wth, l, i, 8, hh);
        st16(wtl, l, i, 8, f2bf(v - bf2f(hh)));
      }
    }
    __syncthreads();   // covers x-stage and W^T-stage cross-lane visibility
    f32x4 acc[4][4];
    #pragma unroll
    for(int i = 0; i < 4; i++)
      #pragma unroll
      for(int j = 0; j < 4; j++)
        acc[i][j] = (f32x4){0.f, 0.f, 0.f, 0.f};
    #pragma unroll
    for(int ks = 0; ks < 2; ks++){
      int kc = ks * 32 + lg * 8;
      bf16x8 ah[4], al[4], bh[4], bl[4];
      #pragma unroll
      for(int mt = 0; mt < 4; mt++){
        ah[mt] = frag_ld(xh, mt * 16 + l15, kc, 8);
        al[mt] = frag_ld(xl, mt * 16 + l15, kc, 8);
      }
      #pragma unroll
      for(int nt = 0; nt < 4; nt++){
        bh[nt] = frag_ld(wth, nt * 16 + l15, kc, 8);
        bl[nt] = frag_ld(wtl, nt * 16 + l15, kc, 8);
      }
      #pragma unroll
      for(int mt = 0; mt < 4; mt++)
        #pragma unroll
        for(int nt = 0; nt < 4; nt++){
          acc[mt][nt] = MFMA16(ah[mt], bh[nt], acc[mt][nt], 0, 0, 0);
          acc[mt][nt] = MFMA16(ah[mt], bl[nt], acc[mt][nt], 0, 0, 0);
          acc[mt][nt] = MFMA16(al[mt], bh[nt], acc[mt][nt], 0, 0, 0);
        }
    }
    __syncthreads();   // W^T buffers reused next slot: reads must complete first
    if(slot < 2){
      unsigned* dst = (slot == 0 ? Qp : Kp) + ((size_t)(b * NH + h) * NF + f0) * ND;
      #pragma unroll
      for(int mt = 0; mt < 4; mt++)
        #pragma unroll
        for(int nt = 0; nt < 4; nt++)
          #pragma unroll
          for(int jj = 0; jj < 4; jj++){
            int row = mt * 16 + lg * 4 + jj, col = nt * 16 + l15;
            dst[row * ND + col] = packsplit(acc[mt][nt][jj]);
          }
    } else {
      unsigned* dst = Vtp + (size_t)(b * NH + h) * ND * NF;
      #pragma unroll
      for(int mt = 0; mt < 4; mt++)
        #pragma unroll
        for(int nt = 0; nt < 4; nt++){
          int col = nt * 16 + l15;
          int g = f0 + mt * 16 + lg * 4;
          uint4 pv;
          pv.x = packsplit(acc[mt][nt][0]);
          pv.y = packsplit(acc[mt][nt][1]);
          pv.z = packsplit(acc[mt][nt][2]);
          pv.w = packsplit(acc[mt][nt][3]);
          *(uint4*)(dst + (size_t)col * NF + g) = pv;
        }
    }
  }
}

// ---------------- Kernel 2: fused attention + proj + LN ----------------
// grid 512 (2 blocks/CU); 256 thr = 4 waves, wave w = head w. LDS 65536 B
// (fits default dynamic cap -> no hipFuncSetAttribute; launch path is pure launches).
// KVBLK=32; K and V MFMA fragments loaded DIRECT from packed global planes.
// S transposes through wave-private LDS; the cross-lane store->read dependency
// is ordered by __syncthreads() (R6 failed with no fence: compiler hoisted the
// ds_reads above the cross-lane ds_writes; R5/R2 passed first-validation with
// an asm fence — barriers give the same ordering with no inline asm).
__global__ __launch_bounds__(256, 2) void k_attn(const float* __restrict__ x,
    const unsigned* __restrict__ Qp, const unsigned* __restrict__ Kp,
    const unsigned* __restrict__ Vtp,
    const float* __restrict__ Wo, const float* __restrict__ bo,
    const float* __restrict__ gam, const float* __restrict__ bet,
    float* __restrict__ out){
  // XCD remap (R2-verbatim): all 16 f-tiles of one b on one XCD.
  int blk0 = blockIdx.x;
  int xcd = blk0 & 7, j = blk0 >> 3;
  int b = xcd + ((j >> 4) << 3);
  int f0 = (j & 15) << 6;
  int t = threadIdx.x;
  int w = t >> 6, l = t & 63;
  int l15 = l & 15, lg = l >> 4;
  extern __shared__ char sm[];
  // phase 1: wave-private S tiles, plain padded [64][40] hi/lo (10240 B/wave)
  unsigned short* Sh = (unsigned short*)(sm + w * 10240);
  unsigned short* Sl = Sh + 2560;

  // Q fragments resident (R2-verbatim de-interleave from packed plane)
  bf16x8 qh[4][2], ql[4][2];
  {
    const unsigned* qb = Qp + ((size_t)(b * NH + w) * NF + f0) * ND;
    #pragma unroll
    for(int mt = 0; mt < 4; mt++)
      #pragma unroll
      for(int ks = 0; ks < 2; ks++){
        const uint4* p = (const uint4*)(qb + (mt * 16 + l15) * ND + ks * 32 + lg * 8);
        deint(p[0], p[1], qh[mt][ks], ql[mt][ks]);
      }
  }

  f32x4 oa[4][4];
  #pragma unroll
  for(int i = 0; i < 4; i++)
    #pragma unroll
    for(int jn = 0; jn < 4; jn++)
      oa[i][jn] = (f32x4){0.f, 0.f, 0.f, 0.f};

  const unsigned* Kb = Kp + (size_t)(b * NH + w) * NF * ND;
  const unsigned* Vb = Vtp + (size_t)(b * NH + w) * ND * NF;

  for(int tt = 0; tt < 32; tt++){
    int g0 = tt << 5;
    // K fragments direct: B^T row g = g0+nt*16+l15, elems d = ks*32+lg*8+j
    bf16x8 kfh[2][2], kfl[2][2];
    #pragma unroll
    for(int nt = 0; nt < 2; nt++)
      #pragma unroll
      for(int ks = 0; ks < 2; ks++){
        const uint4* p = (const uint4*)(Kb + (size_t)(g0 + nt * 16 + l15) * ND + ks * 32 + lg * 8);
        deint(p[0], p[1], kfh[nt][ks], kfl[nt][ks]);
      }
    // S = Q K^T : D[m][g]  (A = Q rows m, B = K rows g — R2-exact operand roles)
    f32x4 s[4][2];
    #pragma unroll
    for(int i = 0; i < 4; i++){
      s[i][0] = (f32x4){0.f, 0.f, 0.f, 0.f};
      s[i][1] = (f32x4){0.f, 0.f, 0.f, 0.f};
    }
    #pragma unroll
    for(int ks = 0; ks < 2; ks++){
      #pragma unroll
      for(int mt = 0; mt < 4; mt++)
        #pragma unroll
        for(int nt = 0; nt < 2; nt++){
          s[mt][nt] = MFMA16(qh[mt][ks], kfh[nt][ks], s[mt][nt], 0, 0, 0);
          s[mt][nt] = MFMA16(qh[mt][ks], kfl[nt][ks], s[mt][nt], 0, 0, 0);
          s[mt][nt] = MFMA16(ql[mt][ks], kfh[nt][ks], s[mt][nt], 0, 0, 0);
        }
    }
    // issue V loads early (consumed after S split; latency hidden under VALU)
    uint4 vp[8];
    #pragma unroll
    for(int nt = 0; nt < 4; nt++){
      const uint4* p = (const uint4*)(Vb + (size_t)(nt * 16 + l15) * NF + g0 + lg * 8);
      vp[2 * nt] = p[0];
      vp[2 * nt + 1] = p[1];
    }
    // relu(s/8) -> hi/lo split -> plain S store. elem: m = mt*16+lg*4+jj, g = nt*16+l15
    #pragma unroll
    for(int mt = 0; mt < 4; mt++)
      #pragma unroll
      for(int nt = 0; nt < 2; nt++)
        #pragma unroll
        for(int jj = 0; jj < 4; jj++){
          float v = fmaxf(s[mt][nt][jj] * 0.125f, 0.f);
          unsigned short hh = f2bf(v);
          int so = (mt * 16 + lg * 4 + jj) * 40 + nt * 16 + l15;
          Sh[so] = hh;
          Sl[so] = f2bf(v - bf2f(hh));
        }
    __syncthreads();   // order cross-lane S stores before S fragment reads
    // de-interleave V fragments: B^T row d = nt*16+l15, elems g = lg*8+j (local)
    bf16x8 vfh[4], vfl[4];
    #pragma unroll
    for(int nt = 0; nt < 4; nt++)
      deint(vp[2 * nt], vp[2 * nt + 1], vfh[nt], vfl[nt]);
    // PV: O[m][d] += S[m][g] V^T[d][g]
    #pragma unroll
    for(int mt = 0; mt < 4; mt++){
      bf16x8 sah = *(const bf16x8*)(Sh + (mt * 16 + l15) * 40 + lg * 8);
      bf16x8 sal = *(const bf16x8*)(Sl + (mt * 16 + l15) * 40 + lg * 8);
      #pragma unroll
      for(int nt = 0; nt < 4; nt++){
        oa[mt][nt] = MFMA16(sah, vfh[nt], oa[mt][nt], 0, 0, 0);
        oa[mt][nt] = MFMA16(sah, vfl[nt], oa[mt][nt], 0, 0, 0);
        oa[mt][nt] = MFMA16(sal, vfh[nt], oa[mt][nt], 0, 0, 0);
      }
    }
    __syncthreads();   // S reads done before next iteration overwrites the tile
  }

  // phase boundary: repurpose LDS as concat ch/cl (R2-exact); barrier above covers it
  char* ch = sm;             // concat hi [64][256], rsc=32
  char* cl = sm + 32768;     // concat lo
  #pragma unroll
  for(int mt = 0; mt < 4; mt++)
    #pragma unroll
    for(int nt = 0; nt < 4; nt++)
      #pragma unroll
      for(int jj = 0; jj < 4; jj++){
        float v = oa[mt][nt][jj];
        unsigned short hh = f2bf(v);
        int row = mt * 16 + lg * 4 + jj, col = (w << 6) + nt * 16 + l15;
        st16(ch, row, col, 32, hh);
        st16(cl, row, col, 32, f2bf(v - bf2f(hh)));
      }
  __syncthreads();

  // proj: wave w -> local rows w*16..w*16+15 ; P = concat(64x256) . Wo(256x64)
  f32x4 p[4];
  #pragma unroll
  for(int i = 0; i < 4; i++) p[i] = (f32x4){0.f, 0.f, 0.f, 0.f};
  int arow = (w << 4) + l15;
  #pragma unroll
  for(int ks = 0; ks < 8; ks++){
    int kc = ks * 32 + lg * 8;
    bf16x8 ah  = frag_ld(ch, arow, kc, 32);
    bf16x8 al2 = frag_ld(cl, arow, kc, 32);
    #pragma unroll
    for(int nt = 0; nt < 4; nt++){
      // Wo B-frag: B^T row o = nt*16+l15, elems k = kc+j ; Wo[k][o] coalesced rows
      bf16x8 wfh, wfl;
      #pragma unroll
      for(int j2 = 0; j2 < 8; j2++){
        float v = Wo[(size_t)(kc + j2) * ND + nt * 16 + l15];
        unsigned short hh = f2bf(v);
        wfh[j2] = (short)hh;
        wfl[j2] = (short)f2bf(v - bf2f(hh));
      }
      p[nt] = MFMA16(ah,  wfh, p[nt], 0, 0, 0);
      p[nt] = MFMA16(ah,  wfl, p[nt], 0, 0, 0);
      p[nt] = MFMA16(al2, wfh, p[nt], 0, 0, 0);
    }
  }

  float bov[4], gv[4], bv[4];
  #pragma unroll
  for(int nt = 0; nt < 4; nt++){
    int col = nt * 16 + l15;
    bov[nt] = bo[col]; gv[nt] = gam[col]; bv[nt] = bet[col];
  }
  #pragma unroll
  for(int jj = 0; jj < 4; jj++){
    int row = (w << 4) + lg * 4 + jj;
    int frow = f0 + row;
    float vals[4], s1 = 0.f, s2 = 0.f;
    #pragma unroll
    for(int nt = 0; nt < 4; nt++){
      int col = nt * 16 + l15;
      float v = p[nt][jj] + bov[nt] + x[((size_t)b * NF + frow) * ND + col];
      vals[nt] = v; s1 += v; s2 += v * v;
    }
    #pragma unroll
    for(int m = 1; m < 16; m <<= 1){
      s1 += __shfl_xor(s1, m);
      s2 += __shfl_xor(s2, m);
    }
    float mean = s1 * (1.f / 64.f);
    float var  = s2 * (1.f / 64.f) - mean * mean;
    float rs = rsqrtf(var + 1e-5f);
    #pragma unroll
    for(int nt = 0; nt < 4; nt++){
      int col = nt * 16 + l15;
      out[((size_t)b * NF + frow) * ND + col] = (vals[nt] - mean) * rs * gv[nt] + bv[nt];
    }
  }
}

extern "C" void kernel_launch(void* const* d_in, const int* in_sizes, int n_in,
                              void* d_out, int out_size, void* d_ws, size_t ws_size,
                              hipStream_t stream){
  const float* x   = (const float*)d_in[0];
  const float* Wq  = (const float*)d_in[1];
  const float* Wo  = (const float*)d_in[2];
  const float* bo  = (const float*)d_in[3];
  const float* gam = (const float*)d_in[4];
  const float* bet = (const float*)d_in[5];
  float* out = (float*)d_out;

  // workspace: Q, K as [B][H][F][D] pair-dwords; V^T as [B][H][D][F]. 96 MiB (R2-proven).
  unsigned* Qp = (unsigned*)d_ws;
  size_t n1 = (size_t)NB * NH * NF * ND;
  unsigned* Kp  = Qp + n1;
  unsigned* Vtp = Kp + n1;

  (void)in_sizes; (void)n_in; (void)out_size; (void)ws_size;

  k_qkv<<<dim3(NB * 16 * NH), dim3(64), 0, stream>>>(x, Wq, Qp, Kp, Vtp);
  k_attn<<<dim3(NB * 16), dim3(256), 65536, stream>>>(x, Qp, Kp, Vtp, Wo, bo, gam, bet, out);
}